// Round 9
// baseline (212.397 us; speedup 1.0000x reference)
//
#include <hip/hip_runtime.h>

// Problem: B=2, S=2048, D=1024, H=16, HD=64. fp32 in/out.
// Pipeline exploits head-summed K/V: k_sum = x @ (sum_h Wk_h)^T + sum_h bk_h.
//  1. prep_all:     x, Wout -> f16; wcomb=[Wq;Wred] f16; bcomb; zero qf;
//                   fill d_out with bout (bias pre-load for split-K atomics)
//  2. gemm_sk (x2 grid.z): qf += x @ wcomb^T      (split-K=2, fp32 atomics)
//  3. qkv_convert:  qf+bias -> qb(*scale,f16), kb(f16), vtb(V^T,f16)
//  4. flash_attn7:  1 s/wave, 4-wave blocks, 128-t staging, pkrtz P-pack
//  5. gemm_sk (x2 grid.z): d_out += ao @ Wout^T   (split-K=2, fp32 atomics)

#define S_LEN 2048
#define DIM 1024

using floatx4 = __attribute__((ext_vector_type(4))) float;
using halfx8  = __attribute__((ext_vector_type(8))) _Float16;
using halfx4  = __attribute__((ext_vector_type(4))) _Float16;
using fp16x2  = __attribute__((ext_vector_type(2))) __fp16;  // pkrtz ret type

__device__ __forceinline__ floatx4 mfma16(halfx8 a, halfx8 b, floatx4 c) {
  return __builtin_amdgcn_mfma_f32_16x16x32_f16(a, b, c, 0, 0, 0);
}

// async global->LDS, 16B per lane; lds dst is wave-uniform base + lane*16
__device__ __forceinline__ void gll16(const void* g, void* l) {
  __builtin_amdgcn_global_load_lds(
      (const __attribute__((address_space(1))) void*)g,
      (__attribute__((address_space(3))) void*)l, 16, 0, 0);
}

// ---------------- prep: conversions + combined weights + fills ----------------
__global__ __launch_bounds__(256) void prep_all(
    const float* __restrict__ x, const float* __restrict__ wqkv,
    const float* __restrict__ bqkv, const float* __restrict__ wout,
    const float* __restrict__ bout, _Float16* __restrict__ xb,
    _Float16* __restrict__ wcomb, _Float16* __restrict__ woutb,
    float* __restrict__ bcomb, float* __restrict__ qf,
    float* __restrict__ outp) {
  int bx = blockIdx.x;
  if (bx < 6144) {  // fp32 -> f16 conversions
    size_t i4 = ((size_t)bx * 256 + threadIdx.x) * 4;
    const float* src;
    _Float16* dst;
    size_t off;
    if (i4 < 4194304) { src = x; dst = xb; off = i4; }
    else if (i4 < 5242880) { src = wqkv; dst = wcomb; off = i4 - 4194304; }
    else { src = wout; dst = woutb; off = i4 - 5242880; }
    float4 v = *(const float4*)(src + off);
    halfx4 o;
    o[0] = (_Float16)v.x; o[1] = (_Float16)v.y;
    o[2] = (_Float16)v.z; o[3] = (_Float16)v.w;
    *(halfx4*)(dst + off) = o;
  } else if (bx < 6656) {  // head-reduced K/V weights + bcomb
    int gid = (bx - 6144) * 256 + threadIdx.x;  // 131072 threads
    int c = gid >> 10, j = gid & 1023;
    int row0 = (c < 64) ? (1024 + c) : (2048 + c - 64);
    float s = 0.f;
#pragma unroll
    for (int h = 0; h < 16; ++h) s += wqkv[(size_t)(row0 + h * 64) * 1024 + j];
    wcomb[(size_t)1024 * 1024 + gid] = (_Float16)s;
    if (gid < 1024) bcomb[gid] = bqkv[gid];
    if (gid < 128) {
      int b0 = (gid < 64) ? (1024 + gid) : (2048 + gid - 64);
      float sb = 0.f;
#pragma unroll
      for (int h = 0; h < 16; ++h) sb += bqkv[b0 + h * 64];
      bcomb[1024 + gid] = sb;
    }
  } else if (bx < 11264) {  // zero qf (4096 x 1152 fp32)
    size_t i4 = ((size_t)(bx - 6656) * 256 + threadIdx.x) * 4;
    float4 z = {0.f, 0.f, 0.f, 0.f};
    *(float4*)(qf + i4) = z;
  } else {  // fill d_out with bout (bias base for atomic split-K)
    size_t i4 = ((size_t)(bx - 11264) * 256 + threadIdx.x) * 4;
    int col = (int)(i4 & 1023);
    *(float4*)(outp + i4) = *(const float4*)(bout + col);
  }
}

// ------- gemm_sk: 128M x 128N tile, split-K=2, fp32-atomic epilogue -------
// Wave w -> 64x64 quadrant; 4x4 16x16 frags; gll16 staging w/ XOR swizzle.
// blockIdx.z = K-half. C is fp32, pre-initialized (zero or bias); atomicAdd.
__global__ __launch_bounds__(256, 2) void gemm_sk(
    const _Float16* __restrict__ A, const _Float16* __restrict__ W,
    float* __restrict__ C, int ldc) {
  const int K = 1024;
  __shared__ _Float16 As[128][64];  // 16 KB
  __shared__ _Float16 Ws[128][64];  // 16 KB
  int tid = threadIdx.x;
  int lane = tid & 63, w = tid >> 6, ln = lane & 15, q4 = lane >> 4;
  int m0 = blockIdx.x * 128, n0 = blockIdx.y * 128;
  int kb0 = blockIdx.z * 512;
  int mh = (w & 1) * 64, nh = (w >> 1) * 64;
  int rr = lane >> 3, gg = ((lane & 7) ^ rr) * 8;
  const _Float16* agp = A + (size_t)(m0 + w * 32 + rr) * K + kb0 + gg;
  const _Float16* wgp = W + (size_t)(n0 + w * 32 + rr) * K + kb0 + gg;
  floatx4 acc[4][4] = {};
  for (int kt = 0; kt < 512; kt += 64) {
    __syncthreads();
#pragma unroll
    for (int j = 0; j < 4; ++j) {
      gll16(agp + (size_t)(8 * j) * K + kt, &As[w * 32 + 8 * j][0]);
      gll16(wgp + (size_t)(8 * j) * K + kt, &Ws[w * 32 + 8 * j][0]);
    }
    __syncthreads();
#pragma unroll
    for (int kh = 0; kh < 2; ++kh) {
      int sw = ((q4 + 4 * kh) ^ (ln & 7)) * 8;
      halfx8 bf[4];
#pragma unroll
      for (int nf = 0; nf < 4; ++nf)
        bf[nf] = *(const halfx8*)&Ws[nh + nf * 16 + ln][sw];
#pragma unroll
      for (int mf = 0; mf < 4; ++mf) {
        halfx8 af = *(const halfx8*)&As[mh + mf * 16 + ln][sw];
#pragma unroll
        for (int nf = 0; nf < 4; ++nf)
          acc[mf][nf] = mfma16(af, bf[nf], acc[mf][nf]);
      }
    }
  }
#pragma unroll
  for (int nf = 0; nf < 4; ++nf) {
    int col = n0 + nh + nf * 16 + ln;
#pragma unroll
    for (int mf = 0; mf < 4; ++mf) {
      int row = m0 + mh + mf * 16 + q4 * 4;
#pragma unroll
      for (int i = 0; i < 4; ++i)
        atomicAdd(&C[(size_t)(row + i) * ldc + col], acc[mf][nf][i]);
    }
  }
}

// ---------------- qkv_convert: qf + bias -> qb, kb, vtb ----------------
__global__ __launch_bounds__(256) void qkv_convert(
    const float* __restrict__ qf, const float* __restrict__ bcomb,
    _Float16* __restrict__ qb, _Float16* __restrict__ kbo,
    _Float16* __restrict__ vto) {
  const float qscale = 0.18033688011112042f;  // (1/sqrt(64)) * log2(e)
  int bx = blockIdx.x;
  if (bx < 4096) {  // Q: 4096 rows x 1024 cols
    size_t gid = (size_t)bx * 256 + threadIdx.x;
    int row = (int)(gid >> 8), col = ((int)gid & 255) * 4;
    float4 v = *(const float4*)(qf + (size_t)row * 1152 + col);
    float4 bv = *(const float4*)(bcomb + col);
    halfx4 o;
    o[0] = (_Float16)((v.x + bv.x) * qscale);
    o[1] = (_Float16)((v.y + bv.y) * qscale);
    o[2] = (_Float16)((v.z + bv.z) * qscale);
    o[3] = (_Float16)((v.w + bv.w) * qscale);
    *(halfx4*)(qb + (size_t)row * 1024 + col) = o;
  } else {  // KV: 4096 rows x 128 cols
    int gid = (bx - 4096) * 256 + threadIdx.x;  // 131072 threads
    int row = gid >> 5, c = (gid & 31) * 4;
    float4 v = *(const float4*)(qf + (size_t)row * 1152 + 1024 + c);
    float4 bv = *(const float4*)(bcomb + 1024 + c);
    float r0 = v.x + bv.x, r1 = v.y + bv.y, r2 = v.z + bv.z, r3 = v.w + bv.w;
    if (c < 64) {  // k_sum
      halfx4 o;
      o[0] = (_Float16)r0; o[1] = (_Float16)r1;
      o[2] = (_Float16)r2; o[3] = (_Float16)r3;
      *(halfx4*)(kbo + (size_t)row * 64 + c) = o;
    } else {  // v_sum -> transposed vtb[(b*64+d)*S + s]
      int bb = row >> 11, s = row & 2047;
      int d = c - 64;
      vto[((size_t)((bb << 6) + d + 0)) * S_LEN + s] = (_Float16)r0;
      vto[((size_t)((bb << 6) + d + 1)) * S_LEN + s] = (_Float16)r1;
      vto[((size_t)((bb << 6) + d + 2)) * S_LEN + s] = (_Float16)r2;
      vto[((size_t)((bb << 6) + d + 3)) * S_LEN + s] = (_Float16)r3;
    }
  }
}

// ---------------- flash v7: 1 s/wave, 128-t staging, pkrtz pack ----------------
__global__ __launch_bounds__(256, 4) void flash_attn7(
    const _Float16* __restrict__ Qb, const _Float16* __restrict__ kb,
    const _Float16* __restrict__ vtb, _Float16* __restrict__ aob) {
  __shared__ _Float16 Ks[128][64];    // K tile [t][d], XOR-swizzled groups
  __shared__ _Float16 Vt[64][128];    // V^T tile [d][t], per-64-half swizzle
  __shared__ _Float16 Ps[4][16][72];  // per-wave P[h][t]
  int tid = threadIdx.x;
  int lane = tid & 63, w = tid >> 6, ln = lane & 15, q4 = lane >> 4;
  int idx = 1023 - (int)blockIdx.x;   // longest chunks first
  int c = idx >> 1, b = idx & 1;
  int s0 = c * 4;
  int s = s0 + w;
  size_t bS = (size_t)b * S_LEN;

  const _Float16* qp = Qb + (bS + s) * DIM + ln * 64 + q4 * 8;
  halfx8 bq0 = *(const halfx8*)qp, bq1 = *(const halfx8*)(qp + 32);

  float m_run = -1e30f, l_run = 0.f;
  floatx4 oacc[4] = {};

  int rr = lane >> 3, ggk = ((lane & 7) ^ rr) * 8;
  const _Float16* kgp = kb + (bS + w * 32 + rr) * 64 + ggk;
  int vrow = (lane >> 4);
  int vhalf = (lane >> 3) & 1, vg = lane & 7;
  const _Float16* vgp[4];
#pragma unroll
  for (int j = 0; j < 4; ++j) {
    int row = w * 16 + 4 * j + vrow;
    vgp[j] = vtb + ((size_t)b * 64 + row) * S_LEN + vhalf * 64 +
             ((vg ^ (row & 7)) * 8);
  }
  int swk0 = (q4 ^ (ln & 7)) * 8;
  int swk1 = ((q4 + 4) ^ (ln & 7)) * 8;
  _Float16* Pw = &Ps[w][0][0];
  int nt = (s0 >> 7) + 1;

  for (int it = 0; it < nt; ++it) {
    int t0 = it << 7;
    __syncthreads();
#pragma unroll
    for (int j = 0; j < 4; ++j) {
      gll16(kgp + (size_t)(t0 + 8 * j) * 64, &Ks[w * 32 + 8 * j][0]);
      gll16(vgp[j] + t0, &Vt[w * 16 + 4 * j][0]);
    }
    __syncthreads();

#pragma unroll
    for (int tq = 0; tq < 2; ++tq) {
      int t0q = t0 + tq * 64;
      if (t0q > s) break;  // wave-uniform
      floatx4 sf[4];
#pragma unroll
      for (int tf = 0; tf < 4; ++tf) {
        halfx8 ak0 = *(const halfx8*)&Ks[tq * 64 + tf * 16 + ln][swk0];
        halfx8 ak1 = *(const halfx8*)&Ks[tq * 64 + tf * 16 + ln][swk1];
        floatx4 z = {};
        z = mfma16(ak0, bq0, z);
        sf[tf] = mfma16(ak1, bq1, z);
      }
      if (t0q + 63 > s) {  // causal mask on the boundary sub-tile only
#pragma unroll
        for (int tf = 0; tf < 4; ++tf)
#pragma unroll
          for (int i = 0; i < 4; ++i) {
            int t = t0q + tf * 16 + q4 * 4 + i;
            if (t > s) sf[tf][i] = -1e30f;
          }
      }
      float tm = fmaxf(fmaxf(sf[0][0], sf[0][1]), fmaxf(sf[0][2], sf[0][3]));
#pragma unroll
      for (int tf = 1; tf < 4; ++tf)
        tm = fmaxf(tm, fmaxf(fmaxf(sf[tf][0], sf[tf][1]),
                             fmaxf(sf[tf][2], sf[tf][3])));
      tm = fmaxf(tm, __shfl_xor(tm, 16));
      tm = fmaxf(tm, __shfl_xor(tm, 32));
      float mn = fmaxf(m_run, tm);
      float alpha = exp2f(m_run - mn);
      m_run = mn;
      float rs = 0.f;
#pragma unroll
      for (int tf = 0; tf < 4; ++tf) {
        float p0 = exp2f(sf[tf][0] - mn), p1 = exp2f(sf[tf][1] - mn);
        float p2 = exp2f(sf[tf][2] - mn), p3 = exp2f(sf[tf][3] - mn);
        rs += (p0 + p1) + (p2 + p3);
        union { fp16x2 h2[2]; halfx4 h4; } u;
        u.h2[0] = __builtin_amdgcn_cvt_pkrtz(p0, p1);
        u.h2[1] = __builtin_amdgcn_cvt_pkrtz(p2, p3);
        *(halfx4*)&Pw[ln * 72 + tf * 16 + q4 * 4] = u.h4;
      }
      rs += __shfl_xor(rs, 16);
      rs += __shfl_xor(rs, 32);
      l_run = l_run * alpha + rs;
      halfx8 bp0 = *(const halfx8*)&Pw[ln * 72 + q4 * 8];
      halfx8 bp1 = *(const halfx8*)&Pw[ln * 72 + 32 + q4 * 8];
#pragma unroll
      for (int n2 = 0; n2 < 4; ++n2) {
        halfx8 av0 = *(const halfx8*)&Vt[n2 * 16 + ln][tq * 64 + swk0];
        halfx8 av1 = *(const halfx8*)&Vt[n2 * 16 + ln][tq * 64 + swk1];
#pragma unroll
        for (int i = 0; i < 4; ++i) oacc[n2][i] *= alpha;
        oacc[n2] = mfma16(av0, bp0, oacc[n2]);
        oacc[n2] = mfma16(av1, bp1, oacc[n2]);
      }
    }
  }
  float inv = 1.0f / l_run;
#pragma unroll
  for (int n2 = 0; n2 < 4; ++n2) {
    halfx4 o;
#pragma unroll
    for (int i = 0; i < 4; ++i) o[i] = (_Float16)(oacc[n2][i] * inv);
    *(halfx4*)(aob + (bS + s) * DIM + ln * 64 + n2 * 16 + q4 * 4) = o;
  }
}

extern "C" void kernel_launch(void* const* d_in, const int* in_sizes, int n_in,
                              void* d_out, int out_size, void* d_ws,
                              size_t ws_size, hipStream_t stream) {
  const float* x    = (const float*)d_in[0];
  const float* wqkv = (const float*)d_in[1];
  const float* bqkv = (const float*)d_in[2];
  const float* wout = (const float*)d_in[3];
  const float* bout = (const float*)d_in[4];
  float* out = (float*)d_out;
  char* ws = (char*)d_ws;
  // Workspace (~40.3 MB). xb (gemm0 input) and aob (flash output) share:
  // xb is dead before flash writes aob.
  _Float16* xb    = (_Float16*)(ws);                               // 8 MB
  _Float16* aob   = (_Float16*)(ws);                               // 8 MB (reuse)
  _Float16* qb    = (_Float16*)(ws + (8u << 20));                  // 8 MB
  float*    qf    = (float*)(ws + (16u << 20));                    // 18.87 MB
  _Float16* kb    = (_Float16*)(ws + (35u << 20));                 // 512 KB
  _Float16* vtb   = (_Float16*)(ws + (35u << 20) + (512u << 10));  // 512 KB
  _Float16* wcomb = (_Float16*)(ws + (36u << 20));                 // 2.25 MB
  _Float16* woutb = (_Float16*)(ws + (38u << 20) + (512u << 10));  // 2 MB
  float*    bcomb = (float*)(ws + (40u << 20) + (512u << 10));     // 4.6 KB

  hipLaunchKernelGGL(prep_all, dim3(15360), dim3(256), 0, stream,
                     x, wqkv, bqkv, wout, bout, xb, wcomb, woutb, bcomb, qf,
                     out);
  hipLaunchKernelGGL(gemm_sk, dim3(32, 9, 2), dim3(256), 0, stream,
                     xb, wcomb, qf, 1152);
  hipLaunchKernelGGL(qkv_convert, dim3(4608), dim3(256), 0, stream,
                     qf, bcomb, qb, kb, vtb);
  hipLaunchKernelGGL(flash_attn7, dim3(1024), dim3(256), 0, stream,
                     qb, kb, vtb, aob);
  hipLaunchKernelGGL(gemm_sk, dim3(32, 8, 2), dim3(256), 0, stream,
                     aob, woutb, out, 1024);
}

// Round 10
// 170.357 us; speedup vs baseline: 1.2468x; 1.2468x over previous
//
#include <hip/hip_runtime.h>

// Problem: B=2, S=2048, D=1024, H=16, HD=64. fp32 in/out.
// Pipeline exploits head-summed K/V: k_sum = x @ (sum_h Wk_h)^T + sum_h bk_h.
//  1. prep_all:    x, Wout -> f16; wcomb=[Wq;Wred] f16 (1152x1024); bcomb
//  2. gemm_skp (grid.z=2): f16 partials of x @ wcomb^T (split-K=2, no bias)
//  3. qkv_reduce:  p0+p1+bias -> qb(*scale), kb, vtb(V^T)
//  4. flash_attn8: 1 s/wave, 128-t softmax step (one reduce/alpha per 128 t)
//  5. gemm_skp (grid.z=2): f16 partials of ao @ Wout^T
//  6. out_reduce:  p0+p1+bout -> d_out (fp32)

#define S_LEN 2048
#define DIM 1024

using floatx4 = __attribute__((ext_vector_type(4))) float;
using halfx8  = __attribute__((ext_vector_type(8))) _Float16;
using halfx4  = __attribute__((ext_vector_type(4))) _Float16;
using fp16x2  = __attribute__((ext_vector_type(2))) __fp16;  // pkrtz ret type

__device__ __forceinline__ floatx4 mfma16(halfx8 a, halfx8 b, floatx4 c) {
  return __builtin_amdgcn_mfma_f32_16x16x32_f16(a, b, c, 0, 0, 0);
}

// async global->LDS, 16B per lane; lds dst is wave-uniform base + lane*16
__device__ __forceinline__ void gll16(const void* g, void* l) {
  __builtin_amdgcn_global_load_lds(
      (const __attribute__((address_space(1))) void*)g,
      (__attribute__((address_space(3))) void*)l, 16, 0, 0);
}

// ---------------- prep: conversions + combined weights ----------------
__global__ __launch_bounds__(256) void prep_all(
    const float* __restrict__ x, const float* __restrict__ wqkv,
    const float* __restrict__ bqkv, const float* __restrict__ wout,
    _Float16* __restrict__ xb, _Float16* __restrict__ wcomb,
    _Float16* __restrict__ woutb, float* __restrict__ bcomb) {
  int bx = blockIdx.x;
  if (bx < 6144) {
    size_t i4 = ((size_t)bx * 256 + threadIdx.x) * 4;
    const float* src;
    _Float16* dst;
    size_t off;
    if (i4 < 4194304) { src = x; dst = xb; off = i4; }
    else if (i4 < 5242880) { src = wqkv; dst = wcomb; off = i4 - 4194304; }
    else { src = wout; dst = woutb; off = i4 - 5242880; }
    float4 v = *(const float4*)(src + off);
    halfx4 o;
    o[0] = (_Float16)v.x; o[1] = (_Float16)v.y;
    o[2] = (_Float16)v.z; o[3] = (_Float16)v.w;
    *(halfx4*)(dst + off) = o;
  } else {
    int gid = (bx - 6144) * 256 + threadIdx.x;  // 131072 threads
    int c = gid >> 10, j = gid & 1023;
    int row0 = (c < 64) ? (1024 + c) : (2048 + c - 64);
    float s = 0.f;
#pragma unroll
    for (int h = 0; h < 16; ++h) s += wqkv[(size_t)(row0 + h * 64) * 1024 + j];
    wcomb[(size_t)1024 * 1024 + gid] = (_Float16)s;
    if (gid < 1024) bcomb[gid] = bqkv[gid];
    if (gid < 128) {
      int b0 = (gid < 64) ? (1024 + gid) : (2048 + gid - 64);
      float sb = 0.f;
#pragma unroll
      for (int h = 0; h < 16; ++h) sb += bqkv[b0 + h * 64];
      bcomb[1024 + gid] = sb;
    }
  }
}

// -------- gemm_skp: 128M x 128N tile, split-K=2, f16 partial output --------
// Wave w -> 64x64 quadrant; 4x4 16x16 frags; gll16 staging w/ XOR swizzle.
// blockIdx.z = K-half; partial z written at P + z*4096*ldc. No bias here.
__global__ __launch_bounds__(256, 2) void gemm_skp(
    const _Float16* __restrict__ A, const _Float16* __restrict__ W,
    _Float16* __restrict__ P, int ldc) {
  const int K = 1024;
  __shared__ _Float16 As[128][64];  // 16 KB
  __shared__ _Float16 Ws[128][64];  // 16 KB
  int tid = threadIdx.x;
  int lane = tid & 63, w = tid >> 6, ln = lane & 15, q4 = lane >> 4;
  int m0 = blockIdx.x * 128, n0 = blockIdx.y * 128;
  int kb0 = blockIdx.z * 512;
  int mh = (w & 1) * 64, nh = (w >> 1) * 64;
  int rr = lane >> 3, gg = ((lane & 7) ^ rr) * 8;
  const _Float16* agp = A + (size_t)(m0 + w * 32 + rr) * K + kb0 + gg;
  const _Float16* wgp = W + (size_t)(n0 + w * 32 + rr) * K + kb0 + gg;
  _Float16* Pz = P + (size_t)blockIdx.z * 4096 * ldc;
  floatx4 acc[4][4] = {};
  for (int kt = 0; kt < 512; kt += 64) {
    __syncthreads();
#pragma unroll
    for (int j = 0; j < 4; ++j) {
      gll16(agp + (size_t)(8 * j) * K + kt, &As[w * 32 + 8 * j][0]);
      gll16(wgp + (size_t)(8 * j) * K + kt, &Ws[w * 32 + 8 * j][0]);
    }
    __syncthreads();
#pragma unroll
    for (int kh = 0; kh < 2; ++kh) {
      int sw = ((q4 + 4 * kh) ^ (ln & 7)) * 8;
      halfx8 bf[4];
#pragma unroll
      for (int nf = 0; nf < 4; ++nf)
        bf[nf] = *(const halfx8*)&Ws[nh + nf * 16 + ln][sw];
#pragma unroll
      for (int mf = 0; mf < 4; ++mf) {
        halfx8 af = *(const halfx8*)&As[mh + mf * 16 + ln][sw];
#pragma unroll
        for (int nf = 0; nf < 4; ++nf)
          acc[mf][nf] = mfma16(af, bf[nf], acc[mf][nf]);
      }
    }
  }
#pragma unroll
  for (int nf = 0; nf < 4; ++nf) {
    int col = n0 + nh + nf * 16 + ln;
#pragma unroll
    for (int mf = 0; mf < 4; ++mf) {
      int row = m0 + mh + mf * 16 + q4 * 4;
#pragma unroll
      for (int i = 0; i < 4; ++i)
        Pz[(size_t)(row + i) * ldc + col] = (_Float16)acc[mf][nf][i];
    }
  }
}

// -------- qkv_reduce: partials + bias -> qb(*scale), kb, vtb(V^T) --------
__global__ __launch_bounds__(256) void qkv_reduce(
    const _Float16* __restrict__ P, const float* __restrict__ bcomb,
    _Float16* __restrict__ qb, _Float16* __restrict__ kbo,
    _Float16* __restrict__ vto) {
  const float qscale = 0.18033688011112042f;  // (1/sqrt(64)) * log2(e)
  const size_t PZ = (size_t)4096 * 1152;
  int bx = blockIdx.x;
  if (bx < 4096) {  // Q: row = bx, 256 thr x 4 cols
    int row = bx, col = threadIdx.x * 4;
    halfx4 a = *(const halfx4*)(P + (size_t)row * 1152 + col);
    halfx4 b = *(const halfx4*)(P + PZ + (size_t)row * 1152 + col);
    float4 bv = *(const float4*)(bcomb + col);
    halfx4 o;
    o[0] = (_Float16)(((float)a[0] + (float)b[0] + bv.x) * qscale);
    o[1] = (_Float16)(((float)a[1] + (float)b[1] + bv.y) * qscale);
    o[2] = (_Float16)(((float)a[2] + (float)b[2] + bv.z) * qscale);
    o[3] = (_Float16)(((float)a[3] + (float)b[3] + bv.w) * qscale);
    *(halfx4*)(qb + (size_t)row * 1024 + col) = o;
  } else {  // KV: 4096 rows x 128 cols
    int gid = (bx - 4096) * 256 + threadIdx.x;  // 131072 threads
    int row = gid >> 5, c = (gid & 31) * 4;
    halfx4 a = *(const halfx4*)(P + (size_t)row * 1152 + 1024 + c);
    halfx4 b = *(const halfx4*)(P + PZ + (size_t)row * 1152 + 1024 + c);
    float4 bv = *(const float4*)(bcomb + 1024 + c);
    float r0 = (float)a[0] + (float)b[0] + bv.x;
    float r1 = (float)a[1] + (float)b[1] + bv.y;
    float r2 = (float)a[2] + (float)b[2] + bv.z;
    float r3 = (float)a[3] + (float)b[3] + bv.w;
    if (c < 64) {  // k_sum
      halfx4 o;
      o[0] = (_Float16)r0; o[1] = (_Float16)r1;
      o[2] = (_Float16)r2; o[3] = (_Float16)r3;
      *(halfx4*)(kbo + (size_t)row * 64 + c) = o;
    } else {  // v_sum -> transposed vtb[(b*64+d)*S + s]
      int bb = row >> 11, s = row & 2047;
      int d = c - 64;
      vto[((size_t)((bb << 6) + d + 0)) * S_LEN + s] = (_Float16)r0;
      vto[((size_t)((bb << 6) + d + 1)) * S_LEN + s] = (_Float16)r1;
      vto[((size_t)((bb << 6) + d + 2)) * S_LEN + s] = (_Float16)r2;
      vto[((size_t)((bb << 6) + d + 3)) * S_LEN + s] = (_Float16)r3;
    }
  }
}

// -------- out_reduce: partials + bout -> d_out (fp32) --------
__global__ __launch_bounds__(256) void out_reduce(
    const _Float16* __restrict__ P, const float* __restrict__ bout,
    float* __restrict__ out) {
  const size_t PZ = (size_t)4096 * 1024;
  int row = blockIdx.x, col = threadIdx.x * 4;
  halfx4 a = *(const halfx4*)(P + (size_t)row * 1024 + col);
  halfx4 b = *(const halfx4*)(P + PZ + (size_t)row * 1024 + col);
  float4 bv = *(const float4*)(bout + col);
  float4 o;
  o.x = (float)a[0] + (float)b[0] + bv.x;
  o.y = (float)a[1] + (float)b[1] + bv.y;
  o.z = (float)a[2] + (float)b[2] + bv.z;
  o.w = (float)a[3] + (float)b[3] + bv.w;
  *(float4*)(out + (size_t)row * 1024 + col) = o;
}

// -------- flash v8: 1 s/wave, single 128-t softmax step per staging --------
// Same staging/occupancy shape as v7 (proven best); the two 64-t softmax
// sub-steps are merged: one max/alpha/rescale/l-update per 128 t.
__global__ __launch_bounds__(256, 4) void flash_attn8(
    const _Float16* __restrict__ Qb, const _Float16* __restrict__ kb,
    const _Float16* __restrict__ vtb, _Float16* __restrict__ aob) {
  __shared__ _Float16 Ks[128][64];     // K tile [t][d], XOR-swizzled groups
  __shared__ _Float16 Vt[64][128];     // V^T tile [d][t], per-64-half swizzle
  __shared__ _Float16 Ps[4][16][136];  // per-wave P[h][t], t=0..127
  int tid = threadIdx.x;
  int lane = tid & 63, w = tid >> 6, ln = lane & 15, q4 = lane >> 4;
  int idx = 1023 - (int)blockIdx.x;   // longest chunks first
  int c = idx >> 1, b = idx & 1;
  int s0 = c * 4;
  int s = s0 + w;
  size_t bS = (size_t)b * S_LEN;

  const _Float16* qp = Qb + (bS + s) * DIM + ln * 64 + q4 * 8;
  halfx8 bq0 = *(const halfx8*)qp, bq1 = *(const halfx8*)(qp + 32);

  float m_run = -1e30f, l_run = 0.f;
  floatx4 oacc[4] = {};

  int rr = lane >> 3, ggk = ((lane & 7) ^ rr) * 8;
  const _Float16* kgp = kb + (bS + w * 32 + rr) * 64 + ggk;
  int vrow = (lane >> 4);
  int vhalf = (lane >> 3) & 1, vg = lane & 7;
  const _Float16* vgp[4];
#pragma unroll
  for (int j = 0; j < 4; ++j) {
    int row = w * 16 + 4 * j + vrow;
    vgp[j] = vtb + ((size_t)b * 64 + row) * S_LEN + vhalf * 64 +
             ((vg ^ (row & 7)) * 8);
  }
  int swk0 = (q4 ^ (ln & 7)) * 8;
  int swk1 = ((q4 + 4) ^ (ln & 7)) * 8;
  _Float16* Pw = &Ps[w][0][0];
  int nt = (s0 >> 7) + 1;

  for (int it = 0; it < nt; ++it) {
    int t0 = it << 7;
    __syncthreads();
#pragma unroll
    for (int j = 0; j < 4; ++j) {
      gll16(kgp + (size_t)(t0 + 8 * j) * 64, &Ks[w * 32 + 8 * j][0]);
      gll16(vgp[j] + t0, &Vt[w * 16 + 4 * j][0]);
    }
    __syncthreads();

    // S^T = K Q^T (log2 domain): frag tf rows t = t0 + tf*16 + q4*4 + i
    floatx4 sf[8];
#pragma unroll
    for (int tf = 0; tf < 8; ++tf) {
      halfx8 ak0 = *(const halfx8*)&Ks[tf * 16 + ln][swk0];
      halfx8 ak1 = *(const halfx8*)&Ks[tf * 16 + ln][swk1];
      floatx4 z = {};
      z = mfma16(ak0, bq0, z);
      sf[tf] = mfma16(ak1, bq1, z);
    }
    if (t0 + 127 > s) {  // causal mask (earlier tiles provably all t <= s)
#pragma unroll
      for (int tf = 0; tf < 8; ++tf)
#pragma unroll
        for (int i = 0; i < 4; ++i) {
          int t = t0 + tf * 16 + q4 * 4 + i;
          if (t > s) sf[tf][i] = -1e30f;
        }
    }
    // per-head max over 128 t: 32 in-lane + 2 shuffle rounds
    float tm = fmaxf(fmaxf(sf[0][0], sf[0][1]), fmaxf(sf[0][2], sf[0][3]));
#pragma unroll
    for (int tf = 1; tf < 8; ++tf)
      tm = fmaxf(tm, fmaxf(fmaxf(sf[tf][0], sf[tf][1]),
                           fmaxf(sf[tf][2], sf[tf][3])));
    tm = fmaxf(tm, __shfl_xor(tm, 16));
    tm = fmaxf(tm, __shfl_xor(tm, 32));
    float mn = fmaxf(m_run, tm);
    float alpha = exp2f(m_run - mn);
    m_run = mn;
    float rs = 0.f;
#pragma unroll
    for (int tf = 0; tf < 8; ++tf) {
      float p0 = exp2f(sf[tf][0] - mn), p1 = exp2f(sf[tf][1] - mn);
      float p2 = exp2f(sf[tf][2] - mn), p3 = exp2f(sf[tf][3] - mn);
      rs += (p0 + p1) + (p2 + p3);
      union { fp16x2 h2[2]; halfx4 h4; } u;
      u.h2[0] = __builtin_amdgcn_cvt_pkrtz(p0, p1);
      u.h2[1] = __builtin_amdgcn_cvt_pkrtz(p2, p3);
      *(halfx4*)&Pw[ln * 136 + tf * 16 + q4 * 4] = u.h4;
    }
    rs += __shfl_xor(rs, 16);
    rs += __shfl_xor(rs, 32);
    l_run = l_run * alpha + rs;
    // P readback as B-operand over k=t (4 frags of 32 t)
    halfx8 bp[4];
#pragma unroll
    for (int kh = 0; kh < 4; ++kh)
      bp[kh] = *(const halfx8*)&Pw[ln * 136 + kh * 32 + q4 * 8];
#pragma unroll
    for (int n2 = 0; n2 < 4; ++n2)
#pragma unroll
      for (int i = 0; i < 4; ++i) oacc[n2][i] *= alpha;
#pragma unroll
    for (int n2 = 0; n2 < 4; ++n2) {
#pragma unroll
      for (int kh = 0; kh < 4; ++kh) {
        halfx8 av = *(const halfx8*)&Vt[n2 * 16 + ln]
            [(kh >> 1) * 64 + (((q4 + 4 * (kh & 1)) ^ (ln & 7)) * 8)];
        oacc[n2] = mfma16(av, bp[kh], oacc[n2]);
      }
    }
  }
  // epilogue: O^T frag n2: h=ln, d=n2*16+q4*4+i
  float inv = 1.0f / l_run;
#pragma unroll
  for (int n2 = 0; n2 < 4; ++n2) {
    halfx4 o;
#pragma unroll
    for (int i = 0; i < 4; ++i) o[i] = (_Float16)(oacc[n2][i] * inv);
    *(halfx4*)(aob + (bS + s) * DIM + ln * 64 + n2 * 16 + q4 * 4) = o;
  }
}

extern "C" void kernel_launch(void* const* d_in, const int* in_sizes, int n_in,
                              void* d_out, int out_size, void* d_ws,
                              size_t ws_size, hipStream_t stream) {
  const float* x    = (const float*)d_in[0];
  const float* wqkv = (const float*)d_in[1];
  const float* bqkv = (const float*)d_in[2];
  const float* wout = (const float*)d_in[3];
  const float* bout = (const float*)d_in[4];
  float* out = (float*)d_out;
  char* ws = (char*)d_ws;
  // Workspace (~41.6 MB). xb/aob share (xb dead before flash writes aob);
  // QKV partials and out partials share the `part` region (QKV partials
  // dead after qkv_reduce).
  _Float16* xb    = (_Float16*)(ws);                               // 8 MB
  _Float16* aob   = (_Float16*)(ws);                               // (reuse)
  _Float16* qb    = (_Float16*)(ws + (8u << 20));                  // 8 MB
  _Float16* part  = (_Float16*)(ws + (16u << 20));                 // 18.9 MB
  _Float16* kb    = (_Float16*)(ws + (36u << 20));                 // 512 KB
  _Float16* vtb   = (_Float16*)(ws + (36u << 20) + (512u << 10));  // 512 KB
  _Float16* wcomb = (_Float16*)(ws + (37u << 20));                 // 2.25 MB
  _Float16* woutb = (_Float16*)(ws + (39u << 20) + (512u << 10));  // 2 MB
  float*    bcomb = (float*)(ws + (41u << 20) + (512u << 10));     // 4.6 KB

  hipLaunchKernelGGL(prep_all, dim3(6656), dim3(256), 0, stream,
                     x, wqkv, bqkv, wout, xb, wcomb, woutb, bcomb);
  hipLaunchKernelGGL(gemm_skp, dim3(32, 9, 2), dim3(256), 0, stream,
                     xb, wcomb, part, 1152);
  hipLaunchKernelGGL(qkv_reduce, dim3(4608), dim3(256), 0, stream,
                     part, bcomb, qb, kb, vtb);
  hipLaunchKernelGGL(flash_attn8, dim3(1024), dim3(256), 0, stream,
                     qb, kb, vtb, aob);
  hipLaunchKernelGGL(gemm_skp, dim3(32, 8, 2), dim3(256), 0, stream,
                     aob, woutb, part, 1024);
  hipLaunchKernelGGL(out_reduce, dim3(4096), dim3(256), 0, stream,
                     part, bout, out);
}